// Round 1
// baseline (4219.102 us; speedup 1.0000x reference)
//
#include <hip/hip_runtime.h>
#include <hip/hip_fp16.h>

#define HD 128
#define TLEN 49152
#define NBATCH 4
#define NCLS2 256
#define OWLEN 16386
#define NLAY 28
#define NT 128
#define NTHR 512

typedef _Float16 f16;
typedef _Float16 f16x8 __attribute__((ext_vector_type(8)));
typedef _Float16 f16x4 __attribute__((ext_vector_type(4)));
typedef float f32x4 __attribute__((ext_vector_type(4)));
typedef float f32x4u __attribute__((ext_vector_type(4), aligned(4)));

#define MFMA16(a, b, c) __builtin_amdgcn_mfma_f32_16x16x32_f16(a, b, c, 0, 0, 0)

__device__ __forceinline__ float fast_tanh(float x) {
    float e = __expf(-2.f * fabsf(x));
    float t = (1.f - e) / (1.f + e);
    return copysignf(t, x);
}
__device__ __forceinline__ float fast_sig(float x) { return 1.f / (1.f + __expf(-x)); }

// swizzled LDS byte offset for a [rows][128ch] f16 tile (row stride 256B)
__device__ __forceinline__ int swzb(int row, int cb) { return row * 256 + (cb ^ ((row & 7) << 4)); }

// stage a [nrows x 128] fp32 tile (optional per-channel affine) into LDS as swizzled f16
__device__ __forceinline__ void stage_act(const float* __restrict__ src, int tbase, int tlim,
                                          const float* ss, char* dst, int nrows)
{
    int tid = threadIdx.x;
    int cg = tid & 15;
    float sc[8], sh[8];
    if (ss) {
        #pragma unroll
        for (int i = 0; i < 8; ++i) { sc[i] = ss[cg * 8 + i]; sh[i] = ss[128 + cg * 8 + i]; }
    } else {
        #pragma unroll
        for (int i = 0; i < 8; ++i) { sc[i] = 1.f; sh[i] = 0.f; }
    }
    for (int row = tid >> 4; row < nrows; row += 32) {
        int gt = tbase + row;
        f16x8 v;
        if (gt >= 0 && gt < tlim) {
            const float* p = src + (size_t)gt * HD + cg * 8;
            f32x4 a = *(const f32x4*)p;
            f32x4 b = *(const f32x4*)(p + 4);
            #pragma unroll
            for (int i = 0; i < 4; ++i) v[i] = (f16)(a[i] * sc[i] + sh[i]);
            #pragma unroll
            for (int i = 0; i < 4; ++i) v[4 + i] = (f16)(b[i] * sc[4 + i] + sh[4 + i]);
        } else {
            #pragma unroll
            for (int i = 0; i < 8; ++i) v[i] = (f16)0.f;
        }
        *(f16x8*)(dst + swzb(row, cg * 16)) = v;
    }
}

// shared 1x1-conv GEMM + residual/skip/stats epilogue.
// FIRST=1: layer 0 (x broadcast residual, skip_sum WRITE). FIRST=0: normal layer.
template <int FIRST>
__device__ __forceinline__ void w1_epilogue(
    const char* hbuf, const f16* __restrict__ w1, const float* __restrict__ b1,
    const float* __restrict__ xsrc,   // FIRST: x + b*T ; else rin + (b*T+t0)*HD
    const float* ss,                  // LDS scale/shift (null if FIRST)
    float* __restrict__ rout,         // rout + (b*T+t0)*HD
    float* __restrict__ ssum,         // ssum + b*OW*HD
    float* __restrict__ gstats, int layer, int t0,
    float (*slds)[2][HD])
{
    int tid = threadIdx.x;
    int lane = tid & 63, w = tid >> 6;
    int m0 = (w >> 1) * 32, n0 = (w & 1) * 64;
    int lrow = lane & 15, lgrp = lane >> 4;
    const f32x4 fz = {0.f, 0.f, 0.f, 0.f};

    f32x4 sacc[2][4];
    #pragma unroll
    for (int mi = 0; mi < 2; ++mi)
        #pragma unroll
        for (int ni = 0; ni < 4; ++ni) sacc[mi][ni] = fz;

    #pragma unroll
    for (int kk = 0; kk < 4; ++kk) {
        int kr = kk * 32 + lgrp * 8;
        f16x8 a[2], bx[4];
        #pragma unroll
        for (int mi = 0; mi < 2; ++mi)
            a[mi] = *(const f16x8*)(w1 + (m0 + mi * 16 + lrow) * HD + kr);
        #pragma unroll
        for (int ni = 0; ni < 4; ++ni) {
            int t = n0 + ni * 16 + lrow;
            bx[ni] = *(const f16x8*)(hbuf + swzb(t, kr * 2));
        }
        #pragma unroll
        for (int mi = 0; mi < 2; ++mi)
            #pragma unroll
            for (int ni = 0; ni < 4; ++ni)
                sacc[mi][ni] = MFMA16(a[mi], bx[ni], sacc[mi][ni]);
    }

    float b1v[2][4], scv[2][4], shv[2][4];
    #pragma unroll
    for (int mi = 0; mi < 2; ++mi)
        #pragma unroll
        for (int r = 0; r < 4; ++r) {
            int c = m0 + mi * 16 + lgrp * 4 + r;
            b1v[mi][r] = b1[c];
            if (!FIRST) { scv[mi][r] = ss[c]; shv[mi][r] = ss[128 + c]; }
            else { scv[mi][r] = 0.f; shv[mi][r] = 0.f; }
        }

    float s1[2][4] = {}, s2[2][4] = {};
    #pragma unroll
    for (int mi = 0; mi < 2; ++mi) {
        int c0 = m0 + mi * 16 + lgrp * 4;
        #pragma unroll
        for (int ni = 0; ni < 4; ++ni) {
            int tl = n0 + ni * 16 + lrow;
            int gt = t0 + tl;
            f32x4 rv, sk, xv;
            float xb = 0.f;
            if (FIRST) xb = xsrc[gt];
            else       xv = *(const f32x4*)(xsrc + (size_t)tl * HD + c0);
            #pragma unroll
            for (int r = 0; r < 4; ++r) {
                float s = sacc[mi][ni][r] + b1v[mi][r];
                float xn = FIRST ? xb : (xv[r] * scv[mi][r] + shv[mi][r]);
                sk[r] = s;
                rv[r] = s + xn;
                s1[mi][r] += rv[r];
                s2[mi][r] += rv[r] * rv[r];
            }
            *(f32x4*)(rout + (size_t)tl * HD + c0) = rv;
            if (gt >= TLEN - OWLEN) {
                float* sp = ssum + ((size_t)(gt - (TLEN - OWLEN))) * HD + c0;
                if (FIRST) { *(f32x4*)sp = sk; }
                else { f32x4 s0 = *(const f32x4*)sp; s0 += sk; *(f32x4*)sp = s0; }
            }
        }
    }
    #pragma unroll
    for (int msk = 1; msk < 16; msk <<= 1)
        #pragma unroll
        for (int mi = 0; mi < 2; ++mi)
            #pragma unroll
            for (int r = 0; r < 4; ++r) {
                s1[mi][r] += __shfl_xor(s1[mi][r], msk, 16);
                s2[mi][r] += __shfl_xor(s2[mi][r], msk, 16);
            }
    if (lrow == 0) {
        int ng = w & 1;
        #pragma unroll
        for (int mi = 0; mi < 2; ++mi)
            #pragma unroll
            for (int r = 0; r < 4; ++r) {
                int c = m0 + mi * 16 + lgrp * 4 + r;
                slds[ng][0][c] = s1[mi][r];
                slds[ng][1][c] = s2[mi][r];
            }
    }
    __syncthreads();
    if (tid < HD) {
        atomicAdd(&gstats[layer * 256 + tid], slds[0][0][tid] + slds[1][0][tid]);
        atomicAdd(&gstats[layer * 256 + 128 + tid], slds[0][1][tid] + slds[1][1][tid]);
    }
}

__global__ __launch_bounds__(NTHR)
void layer_kernel(const float* __restrict__ rin, float* __restrict__ rout,
                  float* __restrict__ ssum, float* __restrict__ gstats,
                  const f16* __restrict__ wf, const f16* __restrict__ wg,
                  const f16* __restrict__ w1,
                  const float* __restrict__ bf, const float* __restrict__ bg,
                  const float* __restrict__ b1,
                  const float* __restrict__ gamma, const float* __restrict__ beta,
                  int layer, int dil)
{
    __shared__ __align__(16) char xa1[32768];
    __shared__ __align__(16) char xa0[32768];   // tap0 tile, later reused for h
    __shared__ float ss[256];
    float (*slds)[2][HD] = (float (*)[2][HD])xa1;   // reused after f/g GEMM

    int tid = threadIdx.x;
    int b = blockIdx.y;
    int t0 = blockIdx.x * NT;

    // BN params of previous layer (redundant per block; avoids extra launches)
    if (tid < HD) {
        float n = (float)(NBATCH * TLEN);
        float s = gstats[(layer - 1) * 256 + tid];
        float q = gstats[(layer - 1) * 256 + 128 + tid];
        float mean = s / n;
        float var = q / n - mean * mean;
        float sc = gamma[tid] * rsqrtf(var + 1e-5f);
        ss[tid] = sc;
        ss[128 + tid] = beta[tid] - mean * sc;
    }
    __syncthreads();

    const float* rb = rin + (size_t)b * TLEN * HD;
    stage_act(rb, t0, TLEN, ss, xa1, NT);
    stage_act(rb, t0 - dil, TLEN, ss, xa0, NT);
    __syncthreads();

    int lane = tid & 63, w = tid >> 6;
    int m0 = (w >> 1) * 32, n0 = (w & 1) * 64;
    int lrow = lane & 15, lgrp = lane >> 4;
    const f32x4 fz = {0.f, 0.f, 0.f, 0.f};

    f32x4 facc[2][4], gacc[2][4];
    #pragma unroll
    for (int mi = 0; mi < 2; ++mi)
        #pragma unroll
        for (int ni = 0; ni < 4; ++ni) { facc[mi][ni] = fz; gacc[mi][ni] = fz; }

    #pragma unroll
    for (int tap = 0; tap < 2; ++tap) {
        const char* xt = tap ? (const char*)xa1 : (const char*)xa0;
        const f16* wfp = wf + tap * HD * HD;
        const f16* wgp = wg + tap * HD * HD;
        #pragma unroll
        for (int kk = 0; kk < 4; ++kk) {
            int kr = kk * 32 + lgrp * 8;
            f16x8 af[2], ag[2], bx[4];
            #pragma unroll
            for (int mi = 0; mi < 2; ++mi) {
                int o = m0 + mi * 16 + lrow;
                af[mi] = *(const f16x8*)(wfp + o * HD + kr);
                ag[mi] = *(const f16x8*)(wgp + o * HD + kr);
            }
            #pragma unroll
            for (int ni = 0; ni < 4; ++ni) {
                int t = n0 + ni * 16 + lrow;
                bx[ni] = *(const f16x8*)(xt + swzb(t, kr * 2));
            }
            #pragma unroll
            for (int mi = 0; mi < 2; ++mi)
                #pragma unroll
                for (int ni = 0; ni < 4; ++ni) {
                    facc[mi][ni] = MFMA16(af[mi], bx[ni], facc[mi][ni]);
                    gacc[mi][ni] = MFMA16(ag[mi], bx[ni], gacc[mi][ni]);
                }
        }
    }

    float bfv[2][4], bgv[2][4];
    #pragma unroll
    for (int mi = 0; mi < 2; ++mi)
        #pragma unroll
        for (int r = 0; r < 4; ++r) {
            int c = m0 + mi * 16 + lgrp * 4 + r;
            bfv[mi][r] = bf[c];
            bgv[mi][r] = bg[c];
        }

    __syncthreads();   // all xa0 reads done; reuse as h

    #pragma unroll
    for (int mi = 0; mi < 2; ++mi)
        #pragma unroll
        for (int ni = 0; ni < 4; ++ni) {
            int t = n0 + ni * 16 + lrow;
            int c0 = m0 + mi * 16 + lgrp * 4;
            f16x4 hv;
            #pragma unroll
            for (int r = 0; r < 4; ++r) {
                float fv = facc[mi][ni][r] + bfv[mi][r];
                float gv = gacc[mi][ni][r] + bgv[mi][r];
                hv[r] = (f16)(fast_tanh(fv) * fast_sig(gv));
            }
            *(f16x4*)(xa0 + swzb(t, c0 * 2)) = hv;
        }
    __syncthreads();

    w1_epilogue<0>(xa0, w1, b1, rb + (size_t)t0 * HD, ss,
                   rout + ((size_t)b * TLEN + t0) * HD,
                   ssum + (size_t)b * OWLEN * HD,
                   gstats, layer, t0, slds);
}

__global__ __launch_bounds__(NTHR)
void layer0_kernel(const float* __restrict__ x,
                   const float* __restrict__ Wf0, const float* __restrict__ bf0,
                   const float* __restrict__ Wg0, const float* __restrict__ bg0,
                   const f16* __restrict__ w10, const float* __restrict__ b10,
                   float* __restrict__ rout, float* __restrict__ ssum,
                   float* __restrict__ gstats)
{
    __shared__ __align__(16) char hbuf[32768];
    __shared__ float wl[6][HD];
    __shared__ float slds0[2][2][HD];
    int tid = threadIdx.x;
    int b = blockIdx.y;
    int t0 = blockIdx.x * NT;
    if (tid < HD) {
        wl[0][tid] = Wf0[tid * 2 + 0]; wl[1][tid] = Wf0[tid * 2 + 1]; wl[2][tid] = bf0[tid];
        wl[3][tid] = Wg0[tid * 2 + 0]; wl[4][tid] = Wg0[tid * 2 + 1]; wl[5][tid] = bg0[tid];
    }
    __syncthreads();
    const float* xb = x + (size_t)b * TLEN;
    int cg = tid & 15;
    for (int row = tid >> 4; row < NT; row += 32) {
        int gt = t0 + row;
        float xc = xb[gt];
        float xm = (gt >= 1) ? xb[gt - 1] : 0.f;
        f16x8 hv;
        #pragma unroll
        for (int i = 0; i < 8; ++i) {
            int c = cg * 8 + i;
            float fv = wl[0][c] * xm + wl[1][c] * xc + wl[2][c];
            float gv = wl[3][c] * xm + wl[4][c] * xc + wl[5][c];
            hv[i] = (f16)(fast_tanh(fv) * fast_sig(gv));
        }
        *(f16x8*)(hbuf + swzb(row, cg * 16)) = hv;
    }
    __syncthreads();
    w1_epilogue<1>(hbuf, w10, b10, xb, nullptr,
                   rout + ((size_t)b * TLEN + t0) * HD,
                   ssum + (size_t)b * OWLEN * HD,
                   gstats, 0, t0, slds0);
}

__global__ __launch_bounds__(NTHR)
void head_gemm(const float* __restrict__ in, const f16* __restrict__ wm,
               const float* __restrict__ bias, float* __restrict__ out)
{
    __shared__ __align__(16) char xt[32768];
    int tid = threadIdx.x;
    int b = blockIdx.y;
    int t0 = blockIdx.x * NT;
    const float* ib = in + (size_t)b * OWLEN * HD;
    stage_act(ib, t0, OWLEN, nullptr, xt, NT);
    __syncthreads();
    int lane = tid & 63, w = tid >> 6;
    int m0 = (w >> 1) * 32, n0 = (w & 1) * 64;
    int lrow = lane & 15, lgrp = lane >> 4;
    const f32x4 fz = {0.f, 0.f, 0.f, 0.f};
    f32x4 acc[2][4];
    #pragma unroll
    for (int mi = 0; mi < 2; ++mi)
        #pragma unroll
        for (int ni = 0; ni < 4; ++ni) acc[mi][ni] = fz;
    #pragma unroll
    for (int kk = 0; kk < 4; ++kk) {
        int kr = kk * 32 + lgrp * 8;
        f16x8 a[2], bx[4];
        #pragma unroll
        for (int mi = 0; mi < 2; ++mi)
            a[mi] = *(const f16x8*)(wm + (m0 + mi * 16 + lrow) * HD + kr);
        #pragma unroll
        for (int ni = 0; ni < 4; ++ni) {
            int t = n0 + ni * 16 + lrow;
            bx[ni] = *(const f16x8*)(xt + swzb(t, kr * 2));
        }
        #pragma unroll
        for (int mi = 0; mi < 2; ++mi)
            #pragma unroll
            for (int ni = 0; ni < 4; ++ni)
                acc[mi][ni] = MFMA16(a[mi], bx[ni], acc[mi][ni]);
    }
    float* ob = out + (size_t)b * OWLEN * HD;
    #pragma unroll
    for (int mi = 0; mi < 2; ++mi) {
        int c0 = m0 + mi * 16 + lgrp * 4;
        float bv[4];
        #pragma unroll
        for (int r = 0; r < 4; ++r) bv[r] = bias[c0 + r];
        #pragma unroll
        for (int ni = 0; ni < 4; ++ni) {
            int gt = t0 + n0 + ni * 16 + lrow;
            if (gt < OWLEN) {
                f32x4 v;
                #pragma unroll
                for (int r = 0; r < 4; ++r) v[r] = fmaxf(acc[mi][ni][r] + bv[r], 0.f);
                *(f32x4*)(ob + (size_t)gt * HD + c0) = v;
            }
        }
    }
}

__global__ __launch_bounds__(NTHR)
void final_kernel(const float* __restrict__ y2, const f16* __restrict__ whc,
                  const float* __restrict__ bhc, float* __restrict__ out)
{
    __shared__ __align__(16) char yt[130 * 256];
    int tid = threadIdx.x;
    int b = blockIdx.y;
    int t0 = blockIdx.x * NT;
    stage_act(y2 + (size_t)b * OWLEN * HD, t0, OWLEN, nullptr, yt, 130);
    __syncthreads();
    int lane = tid & 63, w = tid >> 6;
    int tw0 = (w & 1) * 64, o0 = (w >> 1) * 64;
    int lrow = lane & 15, lgrp = lane >> 4;
    const f32x4 fz = {0.f, 0.f, 0.f, 0.f};
    f32x4 acc[4][4];
    #pragma unroll
    for (int ti = 0; ti < 4; ++ti)
        #pragma unroll
        for (int oi = 0; oi < 4; ++oi) acc[ti][oi] = fz;
    #pragma unroll
    for (int tap = 0; tap < 2; ++tap) {
        #pragma unroll
        for (int kk = 0; kk < 4; ++kk) {
            int kr = kk * 32 + lgrp * 8;
            f16x8 a[4], bw[4];
            #pragma unroll
            for (int ti = 0; ti < 4; ++ti) {
                int rrow = tw0 + ti * 16 + lrow + tap;
                a[ti] = *(const f16x8*)(yt + swzb(rrow, kr * 2));
            }
            #pragma unroll
            for (int oi = 0; oi < 4; ++oi) {
                int o = o0 + oi * 16 + lrow;
                bw[oi] = *(const f16x8*)(whc + ((size_t)tap * NCLS2 + o) * HD + kr);
            }
            #pragma unroll
            for (int ti = 0; ti < 4; ++ti)
                #pragma unroll
                for (int oi = 0; oi < 4; ++oi)
                    acc[ti][oi] = MFMA16(a[ti], bw[oi], acc[ti][oi]);
        }
    }
    const int OWM = OWLEN - 1;
    #pragma unroll
    for (int oi = 0; oi < 4; ++oi) {
        int o = o0 + oi * 16 + lrow;
        float bh = bhc[o];
        float* orow = out + ((size_t)b * NCLS2 + o) * OWM;
        #pragma unroll
        for (int ti = 0; ti < 4; ++ti) {
            int tbase = t0 + tw0 + ti * 16 + lgrp * 4;
            if (tbase + 3 < OWM) {
                f32x4u v;
                #pragma unroll
                for (int r = 0; r < 4; ++r) v[r] = acc[ti][oi][r] + bh;
                *(f32x4u*)(orow + tbase) = v;
            } else {
                #pragma unroll
                for (int r = 0; r < 4; ++r) {
                    int t = tbase + r;
                    if (t < OWM) orow[t] = acc[ti][oi][r] + bh;
                }
            }
        }
    }
}

__global__ void conv_fg_kernel(const float* __restrict__ wf, const float* __restrict__ wg,
                               f16* __restrict__ wfh, f16* __restrict__ wgh, int total)
{
    int idx = blockIdx.x * blockDim.x + threadIdx.x;
    if (idx >= total) return;
    int i = idx & 127, o = (idx >> 7) & 127, tap = (idx >> 14) & 1, j = idx >> 15;
    int src = ((j * HD + o) * HD + i) * 2 + tap;
    wfh[idx] = (f16)wf[src];
    wgh[idx] = (f16)wg[src];
}
__global__ void conv_cast_kernel(const float* __restrict__ s, f16* __restrict__ d, int n)
{
    int idx = blockIdx.x * blockDim.x + threadIdx.x;
    if (idx < n) d[idx] = (f16)s[idx];
}
__global__ void conv_whc_kernel(const float* __restrict__ s, f16* __restrict__ d)
{
    int idx = blockIdx.x * blockDim.x + threadIdx.x;
    if (idx >= 2 * NCLS2 * HD) return;
    int c = idx & 127, o = (idx >> 7) & 255, tap = idx >> 15;
    d[idx] = (f16)s[(o * HD + c) * 2 + tap];
}

extern "C" void kernel_launch(void* const* d_in, const int* in_sizes, int n_in,
                              void* d_out, int out_size, void* d_ws, size_t ws_size,
                              hipStream_t stream)
{
    const float* x     = (const float*)d_in[0];
    const float* Wf0   = (const float*)d_in[1];
    const float* bf0   = (const float*)d_in[2];
    const float* Wg0   = (const float*)d_in[3];
    const float* bg0   = (const float*)d_in[4];
    const float* W10   = (const float*)d_in[5];
    const float* b10   = (const float*)d_in[6];
    const float* Wf    = (const float*)d_in[7];
    const float* bf    = (const float*)d_in[8];
    const float* Wg    = (const float*)d_in[9];
    const float* bg    = (const float*)d_in[10];
    const float* W1    = (const float*)d_in[11];
    const float* b1    = (const float*)d_in[12];
    const float* gamma = (const float*)d_in[13];
    const float* beta  = (const float*)d_in[14];
    const float* W11   = (const float*)d_in[15];
    const float* b11   = (const float*)d_in[16];
    const float* W12   = (const float*)d_in[17];
    const float* b12   = (const float*)d_in[18];
    const float* Whc   = (const float*)d_in[19];
    const float* bhc   = (const float*)d_in[20];
    float* out = (float*)d_out;

    float* ws = (float*)d_ws;
    const size_t RN = (size_t)NBATCH * TLEN * HD;
    const size_t SSN = (size_t)NBATCH * OWLEN * HD;
    float* rA = ws;
    float* rB = ws + RN;
    float* ssum = ws + 2 * RN;
    float* gstats = ws + 2 * RN + SSN;
    f16* wfh  = (f16*)(ws + 2 * RN + SSN + NLAY * 256);
    f16* wgh  = wfh + 27 * 2 * HD * HD;
    f16* w1h  = wgh + 27 * 2 * HD * HD;
    f16* w10h = w1h + 27 * HD * HD;
    f16* w11h = w10h + HD * HD;
    f16* w12h = w11h + HD * HD;
    f16* whch = w12h + HD * HD;

    hipMemsetAsync(gstats, 0, NLAY * 256 * sizeof(float), stream);

    {
        int total = 27 * 2 * HD * HD;
        conv_fg_kernel<<<(total + 255) / 256, 256, 0, stream>>>(Wf, Wg, wfh, wgh, total);
    }
    conv_cast_kernel<<<(27 * HD * HD + 255) / 256, 256, 0, stream>>>(W1, w1h, 27 * HD * HD);
    conv_cast_kernel<<<(HD * HD + 255) / 256, 256, 0, stream>>>(W10, w10h, HD * HD);
    conv_cast_kernel<<<(HD * HD + 255) / 256, 256, 0, stream>>>(W11, w11h, HD * HD);
    conv_cast_kernel<<<(HD * HD + 255) / 256, 256, 0, stream>>>(W12, w12h, HD * HD);
    conv_whc_kernel<<<(2 * NCLS2 * HD + 255) / 256, 256, 0, stream>>>(Whc, whch);

    dim3 lgrid(TLEN / NT, NBATCH);
    layer0_kernel<<<lgrid, NTHR, 0, stream>>>(x, Wf0, bf0, Wg0, bg0, w10h, b10, rA, ssum, gstats);

    float* rbufs[2] = {rA, rB};
    for (int l = 1; l < NLAY; ++l) {
        int j = l - 1;
        int dil = 1 << (l % 14);
        layer_kernel<<<lgrid, NTHR, 0, stream>>>(
            rbufs[(l - 1) & 1], rbufs[l & 1], ssum, gstats,
            wfh + (size_t)j * 2 * HD * HD, wgh + (size_t)j * 2 * HD * HD,
            w1h + (size_t)j * HD * HD,
            bf + (size_t)j * HD, bg + (size_t)j * HD, b1 + (size_t)j * HD,
            gamma + (size_t)(l - 1) * HD, beta + (size_t)(l - 1) * HD, l, dil);
    }

    dim3 hgrid((OWLEN + NT - 1) / NT, NBATCH);
    head_gemm<<<hgrid, NTHR, 0, stream>>>(ssum, w11h, b11, rA);
    head_gemm<<<hgrid, NTHR, 0, stream>>>(rA, w12h, b12, rB);
    final_kernel<<<hgrid, NTHR, 0, stream>>>(rB, whch, bhc, out);
}